// Round 6
// baseline (116.134 us; speedup 1.0000x reference)
//
#include <hip/hip_runtime.h>
#include <math.h>

// Problem constants
#define BATCH 16
#define CIN 32
#define COUT 96
#define WH 64
#define IMG (WH*WH)              // 4096
#define NPIX (BATCH*IMG)         // 65536 per channel
#define PWELEMS (3*9*32*32)      // 27648 packed bf16 weights
#define XTELEMS (BATCH*IMG*CIN)  // 2097152 bf16 transposed x
#define NBLK 768                 // conv grid: 16 b * 3 cfg * 16 rowg
#define NGRP 96                  // barrier groups of 8 blocks (XCD-local)
#define PAD 16                   // one cacheline (64B) per counter/accumulator
// zero region: gsum[96*16] gsq[96*16] gcnt[96*16] ggo[96*16] root[3*16]
#define ZWORDS (4*NGRP*PAD + 3*PAD)

typedef __attribute__((ext_vector_type(8))) short short8;
typedef __attribute__((ext_vector_type(4))) float floatx4;

__device__ __forceinline__ unsigned short f2bf(float f) {
    union { float f; unsigned u; } v; v.f = f;
    unsigned r = v.u + 0x7FFFu + ((v.u >> 16) & 1u);  // RNE
    return (unsigned short)(r >> 16);
}
__device__ __forceinline__ float bf2f(unsigned short u) {
    union { unsigned u; float f; } v; v.u = (unsigned)u << 16; return v.f;
}

#define GLDS(src, dst) __builtin_amdgcn_global_load_lds( \
    (const __attribute__((address_space(1))) void*)(src), \
    (__attribute__((address_space(3))) void*)(dst), 16, 0, 0)

__device__ __forceinline__ float fast_tanh(float xv) {
    float e = __expf(2.0f * xv);
    return fmaf(-2.0f, __builtin_amdgcn_rcpf(e + 1.0f), 1.0f);
}

// ---------------------------------------------------------------------------
// prep: blocks 0..511 transpose x -> xT[b][pix][c] bf16 ; blocks 512..619
// pack weights -> pw ; block 620 zeroes the barrier/stat region (ws is
// re-poisoned every iteration). Kernel-boundary release makes zeros visible.
// ---------------------------------------------------------------------------
__global__ __launch_bounds__(256) void prep_kernel(
    const float* __restrict__ x, const float* __restrict__ w,
    unsigned short* __restrict__ xT, unsigned short* __restrict__ pw,
    unsigned* __restrict__ zbase)
{
    int blk = blockIdx.x;
    if (blk < 512) {
        int gid  = blk * 256 + threadIdx.x;  // 131072 half-jobs
        int pt   = gid >> 1;                 // b*4096 + pix
        int half = gid & 1;
        int b    = pt >> 12;
        int pix  = pt & 4095;
        const float* xb = x + ((size_t)b * CIN + half * 16) * IMG + pix;
        unsigned packed[8];
#pragma unroll
        for (int c2 = 0; c2 < 8; c2++) {
            unsigned short lo = f2bf(xb[(size_t)(2 * c2) * IMG]);
            unsigned short hi = f2bf(xb[(size_t)(2 * c2 + 1) * IMG]);
            packed[c2] = (unsigned)lo | ((unsigned)hi << 16);
        }
        uint4* dst = (uint4*)(xT + (size_t)pt * 32 + half * 16);
        dst[0] = make_uint4(packed[0], packed[1], packed[2], packed[3]);
        dst[1] = make_uint4(packed[4], packed[5], packed[6], packed[7]);
    } else if (blk < 620) {
        int e = (blk - 512) * 256 + threadIdx.x;
        if (e >= PWELEMS) return;
        int cfg = e / (9 * 1024);
        int rem = e % (9 * 1024);
        int tap = rem >> 10;
        int oc  = (rem >> 5) & 31;
        int c   = rem & 31;
        int d   = cfg + 1;
        int du  = tap / 3, dv = tap % 3;
        size_t idx = (((size_t)(cfg * 32 + oc) * CIN + c) * 65 + (32 + (du - 1) * d)) * 65
                     + (32 + (dv - 1) * d);
        pw[e] = f2bf(w[idx]);
    } else {
        for (int i = threadIdx.x; i < ZWORDS; i += 256) zbase[i] = 0u;
    }
}

// ---------------------------------------------------------------------------
// Fused conv + BN + tanh. grid = 768 = 256 CU x 3 blocks/CU, all co-resident
// (LDS 3*41.5KB=124.5 <= 160KB, VGPR ~70 << 170 cap for 12 waves/CU).
// XCD-aware remap (dispatch is round-robin: XCD = bid%8):
//   xcd=bid&7, idx=bid>>3, b=xcd+8*(idx/48), cfg=(idx%48)>>4, rowg=idx&15.
//   => each XCD's 96 blocks touch exactly 2 xT b-slices (512KB, fits 4MB L2)
//   -> staging reads become L2 hits (~7x row reuse), arrival skew shrinks.
// Stats: per-channel accumulators padded to one line each.
// Barrier: hierarchical + XCD-LOCAL groups (cfg,xcd,rowg-quad: 8 members all
//   on one XCD) and PER-CFG roots: a cfg's 256 blocks release independently.
//   All ops RELAXED agent-scope (data lives at LLC; release would emit
//   buffer_wbl2 per arrive = round-2's 30us stall).
// ---------------------------------------------------------------------------
__global__ __launch_bounds__(256, 3) void conv_bn_kernel(
    const unsigned short* __restrict__ xT, const unsigned short* __restrict__ pw,
    float* __restrict__ gsum, float* __restrict__ gsq,
    unsigned* __restrict__ gcnt, unsigned* __restrict__ ggo,
    unsigned* __restrict__ root,
    const float* __restrict__ gamma, const float* __restrict__ beta,
    float* __restrict__ out)
{
    // 10 rows (i0-3 .. i0+6, circular) x 64 cols x 32 ch bf16 = 40 KB
    __shared__ __align__(16) unsigned short tile[10 * 2048];
    __shared__ float red_s[4][32];
    __shared__ float red_q[4][32];
    __shared__ float sc_a[32];
    __shared__ float sc_b[32];

    int bid  = blockIdx.x;
    int xcd  = bid & 7;
    int idx  = bid >> 3;                 // 0..95
    int bsel = idx / 48;                 // 0..1
    int r48  = idx % 48;
    int cfg  = r48 >> 4;                 // 0..2
    int rowg = r48 & 15;
    int b    = xcd + 8 * bsel;
    int d    = cfg + 1;
    int i0   = rowg * 4;
    int grp  = cfg * 32 + xcd * 4 + (rowg >> 2);  // 8 XCD-local members

    int t    = threadIdx.x;
    int wv   = t >> 6;
    int lane = t & 63;
    int l15  = lane & 15;
    int quad = lane >> 4;

    const unsigned short* xTb = xT + (size_t)b * IMG * 32;
#pragma unroll
    for (int rr = 0; rr < 10; rr++) {
        int gi = (i0 - 3 + rr) & 63;
        GLDS(xTb + (size_t)gi * 2048 + t * 8, &tile[rr * 2048 + t * 8]);
    }

    const unsigned short* pwc = pw + (size_t)cfg * 9 * 32 * 32;
    short8 af[2][9];
#pragma unroll
    for (int h = 0; h < 2; h++)
#pragma unroll
        for (int tap = 0; tap < 9; tap++)
            af[h][tap] = *(const short8*)(pwc + ((tap * 32 + h * 16 + l15) * 32 + quad * 8));

    // preload gamma/beta (shortens post-barrier critical path)
    float gam = 0.f, bet = 0.f;
    if (t < 32) { gam = gamma[cfg * 32 + t]; bet = beta[cfg * 32 + t]; }

    __syncthreads();  // drains GLDS (vmcnt) for all waves

    float ss[2][4], qq[2][4];
#pragma unroll
    for (int h = 0; h < 2; h++)
#pragma unroll
        for (int r = 0; r < 4; r++) { ss[h][r] = 0.f; qq[h][r] = 0.f; }

    // y kept in regs: ypk[h][r][g] = bf16(cg=2g) | bf16(cg=2g+1)<<16
    unsigned ypk[2][4][2];
    int row = i0 + wv;

#pragma unroll
    for (int cgi = 0; cgi < 4; cgi++) {
        floatx4 a0 = {0.f, 0.f, 0.f, 0.f};
        floatx4 a1 = {0.f, 0.f, 0.f, 0.f};
#pragma unroll
        for (int du = 0; du < 3; du++) {
            int rowloc = wv + 3 + (du - 1) * d;        // 0..9
            const unsigned short* rbase = &tile[rowloc * 2048 + quad * 8];
#pragma unroll
            for (int dv = 0; dv < 3; dv++) {
                int col = (cgi * 16 + l15 + (dv - 1) * d) & 63;
                short8 bf = *(const short8*)(rbase + col * 32);
                a0 = __builtin_amdgcn_mfma_f32_16x16x32_bf16(af[0][du * 3 + dv], bf, a0, 0, 0, 0);
                a1 = __builtin_amdgcn_mfma_f32_16x16x32_bf16(af[1][du * 3 + dv], bf, a1, 0, 0, 0);
            }
        }
#pragma unroll
        for (int r = 0; r < 4; r++) {
            float v0 = a0[r], v1 = a1[r];
            unsigned short h0 = f2bf(v0), h1 = f2bf(v1);
            if (cgi & 1) {
                ypk[0][r][cgi >> 1] |= (unsigned)h0 << 16;
                ypk[1][r][cgi >> 1] |= (unsigned)h1 << 16;
            } else {
                ypk[0][r][cgi >> 1] = (unsigned)h0;
                ypk[1][r][cgi >> 1] = (unsigned)h1;
            }
            ss[0][r] += v0; qq[0][r] = fmaf(v0, v0, qq[0][r]);
            ss[1][r] += v1; qq[1][r] = fmaf(v1, v1, qq[1][r]);
        }
    }

    // reduce over the 16 column-lanes -> per-oc row sums
#pragma unroll
    for (int h = 0; h < 2; h++)
#pragma unroll
        for (int r = 0; r < 4; r++) {
            float s = ss[h][r], q = qq[h][r];
            for (int m = 1; m < 16; m <<= 1) {
                s += __shfl_xor(s, m, 64);
                q += __shfl_xor(q, m, 64);
            }
            if (l15 == 0) {
                red_s[wv][h * 16 + quad * 4 + r] = s;
                red_q[wv][h * 16 + quad * 4 + r] = q;
            }
        }
    __syncthreads();

    // per-(block,channel) atomicAdd; each channel accumulator on its OWN line
    if (t < 32) {
        float S = red_s[0][t] + red_s[1][t] + red_s[2][t] + red_s[3][t];
        atomicAdd(&gsum[(cfg * 32 + t) * PAD], S);
    } else if (t < 64) {
        int o = t - 32;
        float Q = red_q[0][o] + red_q[1][o] + red_q[2][o] + red_q[3][o];
        atomicAdd(&gsq[(cfg * 32 + o) * PAD], Q);
    }
    __syncthreads();   // all waves' atomics completed (vmcnt 0) before arrive

    // ---- hierarchical per-cfg grid barrier (RELAXED, XCD-local spin lines)
    if (t == 0) {
        unsigned r = __hip_atomic_fetch_add(&gcnt[grp * PAD], 1u,
                                            __ATOMIC_RELAXED, __HIP_MEMORY_SCOPE_AGENT);
        if (r == 7u) {   // group complete -> bump this cfg's root
            unsigned rr = __hip_atomic_fetch_add(&root[cfg * PAD], 1u,
                                                 __ATOMIC_RELAXED, __HIP_MEMORY_SCOPE_AGENT);
            if (rr == 31u) {   // cfg complete -> release its 32 groups
                for (int gg = cfg * 32; gg < cfg * 32 + 32; gg++)
                    __hip_atomic_store(&ggo[gg * PAD], 1u,
                                       __ATOMIC_RELAXED, __HIP_MEMORY_SCOPE_AGENT);
            }
        }
        while (__hip_atomic_load(&ggo[grp * PAD], __ATOMIC_RELAXED,
                                 __HIP_MEMORY_SCOPE_AGENT) == 0u)
            __builtin_amdgcn_s_sleep(2);
    }
    __syncthreads();

    // ---- per-channel scale/shift (atomic loads: coherent at LLC)
    if (t < 32) {
        int ch = cfg * 32 + t;
        float S = __hip_atomic_load(&gsum[ch * PAD], __ATOMIC_RELAXED, __HIP_MEMORY_SCOPE_AGENT);
        float Q = __hip_atomic_load(&gsq[ch * PAD],  __ATOMIC_RELAXED, __HIP_MEMORY_SCOPE_AGENT);
        const float inv_n = 1.0f / (float)NPIX;
        float mean = S * inv_n;
        float var  = Q * inv_n - mean * mean;
        float a    = gam * rsqrtf(var + 1e-5f);
        sc_a[t] = a;
        sc_b[t] = bet - mean * a;
    }
    __syncthreads();

    // ---- BN + tanh straight from registers -> fp32 out.
#pragma unroll
    for (int h = 0; h < 2; h++)
#pragma unroll
        for (int r = 0; r < 4; r++) {
            int m0  = quad * 4 + r;
            int chl = h * 16 + m0;
            float a  = sc_a[chl];
            float bb = sc_b[chl];
            float* obase = out + ((size_t)b * COUT + cfg * 32 + chl) * IMG
                               + (size_t)row * WH + l15;
#pragma unroll
            for (int g = 0; g < 2; g++) {
                unsigned pk = ypk[h][r][g];
                obase[(2 * g) * 16]     = fast_tanh(fmaf(bf2f((unsigned short)(pk & 0xffffu)), a, bb));
                obase[(2 * g + 1) * 16] = fast_tanh(fmaf(bf2f((unsigned short)(pk >> 16)), a, bb));
            }
        }
}

extern "C" void kernel_launch(void* const* d_in, const int* in_sizes, int n_in,
                              void* d_out, int out_size, void* d_ws, size_t ws_size,
                              hipStream_t stream) {
    const float* x     = (const float*)d_in[0];
    const float* w     = (const float*)d_in[1];
    // d_in[2] = mask: tap positions known analytically (3x3 dilated, centered at 32)
    const float* gamma = (const float*)d_in[3];
    const float* beta  = (const float*)d_in[4];
    float* out = (float*)d_out;

    // transient state in d_ws — no d_out aliasing anywhere
    unsigned short* xT = (unsigned short*)d_ws;             // 2097152 bf16 (4 MB)
    unsigned short* pw = xT + XTELEMS;                      // 27648 bf16
    float* gsum = (float*)(pw + PWELEMS + 32);              // 96 lines
    float* gsq  = gsum + NGRP * PAD;                        // 96 lines
    unsigned* gcnt = (unsigned*)(gsq + NGRP * PAD);         // 96 lines
    unsigned* ggo  = gcnt + NGRP * PAD;                     // 96 lines
    unsigned* root = ggo + NGRP * PAD;                      // 3 lines

    prep_kernel<<<621, 256, 0, stream>>>(x, w, xT, pw, (unsigned*)gsum);
    conv_bn_kernel<<<NBLK, 256, 0, stream>>>(xT, pw, gsum, gsq, gcnt, ggo, root,
                                             gamma, beta, out);
}

// Round 7
// 116.129 us; speedup vs baseline: 1.0000x; 1.0000x over previous
//
#include <hip/hip_runtime.h>
#include <math.h>

// Problem constants
#define BATCH 16
#define CIN 32
#define COUT 96
#define WH 64
#define IMG (WH*WH)              // 4096
#define NPIX (BATCH*IMG)         // 65536 per channel
#define PWELEMS (3*9*32*32)      // 27648 packed bf16 weights
#define XTELEMS (BATCH*IMG*CIN)  // 2097152 bf16 transposed x
#define NBLK 768                 // conv grid: 16 b * 3 cfg * 16 rowg
#define NGRP 96                  // barrier groups of 8 blocks (XCD-local)
#define PAD 16                   // one cacheline (64B) per counter/accumulator
// zero region: gsum[96*16] gsq[96*16] gcnt[96*16] ggo[96*16] root[3*16]
#define ZWORDS (4*NGRP*PAD + 3*PAD)

typedef __attribute__((ext_vector_type(8))) short short8;
typedef __attribute__((ext_vector_type(4))) float floatx4;

__device__ __forceinline__ unsigned short f2bf(float f) {
    union { float f; unsigned u; } v; v.f = f;
    unsigned r = v.u + 0x7FFFu + ((v.u >> 16) & 1u);  // RNE
    return (unsigned short)(r >> 16);
}
__device__ __forceinline__ float bf2f(unsigned short u) {
    union { unsigned u; float f; } v; v.u = (unsigned)u << 16; return v.f;
}

#define GLDS(src, dst) __builtin_amdgcn_global_load_lds( \
    (const __attribute__((address_space(1))) void*)(src), \
    (__attribute__((address_space(3))) void*)(dst), 16, 0, 0)

__device__ __forceinline__ float fast_tanh(float xv) {
    float e = __expf(2.0f * xv);
    return fmaf(-2.0f, __builtin_amdgcn_rcpf(e + 1.0f), 1.0f);
}

// ---------------------------------------------------------------------------
// prep: blocks 0..511 transpose x -> xT[b][pix][c] bf16 ; blocks 512..619
// pack weights -> pw ; block 620 zeroes the barrier/stat region (ws is
// re-poisoned every iteration). Kernel-boundary release makes zeros visible.
// ---------------------------------------------------------------------------
__global__ __launch_bounds__(256) void prep_kernel(
    const float* __restrict__ x, const float* __restrict__ w,
    unsigned short* __restrict__ xT, unsigned short* __restrict__ pw,
    unsigned* __restrict__ zbase)
{
    int blk = blockIdx.x;
    if (blk < 512) {
        int gid  = blk * 256 + threadIdx.x;  // 131072 half-jobs
        int pt   = gid >> 1;                 // b*4096 + pix
        int half = gid & 1;
        int b    = pt >> 12;
        int pix  = pt & 4095;
        const float* xb = x + ((size_t)b * CIN + half * 16) * IMG + pix;
        unsigned packed[8];
#pragma unroll
        for (int c2 = 0; c2 < 8; c2++) {
            unsigned short lo = f2bf(xb[(size_t)(2 * c2) * IMG]);
            unsigned short hi = f2bf(xb[(size_t)(2 * c2 + 1) * IMG]);
            packed[c2] = (unsigned)lo | ((unsigned)hi << 16);
        }
        uint4* dst = (uint4*)(xT + (size_t)pt * 32 + half * 16);
        dst[0] = make_uint4(packed[0], packed[1], packed[2], packed[3]);
        dst[1] = make_uint4(packed[4], packed[5], packed[6], packed[7]);
    } else if (blk < 620) {
        int e = (blk - 512) * 256 + threadIdx.x;
        if (e >= PWELEMS) return;
        int cfg = e / (9 * 1024);
        int rem = e % (9 * 1024);
        int tap = rem >> 10;
        int oc  = (rem >> 5) & 31;
        int c   = rem & 31;
        int d   = cfg + 1;
        int du  = tap / 3, dv = tap % 3;
        size_t idx = (((size_t)(cfg * 32 + oc) * CIN + c) * 65 + (32 + (du - 1) * d)) * 65
                     + (32 + (dv - 1) * d);
        pw[e] = f2bf(w[idx]);
    } else {
        for (int i = threadIdx.x; i < ZWORDS; i += 256) zbase[i] = 0u;
    }
}

// ---------------------------------------------------------------------------
// Fused conv + BN + tanh. grid = 768 = 256 CU x 3 blocks/CU, all co-resident
// (LDS 3*49.3KB=148 <= 160KB, VGPR ~70 << 170 cap for 12 waves/CU).
// KEY CHANGE (R7): wave-PRIVATE row staging. Wave wv reads only rowlocs
//   {wv+3-d, wv+3, wv+3+d} — exactly 3 rows, never another wave's rows.
//   So each wave GLDS-stages its own 3 rows (12 loads) into a private LDS
//   region, overlaps the latency with its 18 af weight loads, and proceeds
//   after a PER-WAVE s_waitcnt vmcnt(0). The old 10-row shared tile +
//   block-wide __syncthreads (slowest-wave coupling, stage/compute
//   serialization — the unexplained ~8us of phase B) is gone.
// XCD-aware remap (dispatch round-robin, XCD = bid%8) keeps each XCD on 2
//   xT b-slices (L2-resident) and each CU mostly on one cfg's weight table.
// Stats: per-channel accumulators padded to one line each; device-scope
//   atomicAdd -> LLC (coherent across XCDs).
// Barrier: hierarchical, XCD-local groups, per-cfg roots, all RELAXED
//   agent-scope (release would emit buffer_wbl2 per arrive = R2's stall).
// ---------------------------------------------------------------------------
__global__ __launch_bounds__(256, 3) void conv_bn_kernel(
    const unsigned short* __restrict__ xT, const unsigned short* __restrict__ pw,
    float* __restrict__ gsum, float* __restrict__ gsq,
    unsigned* __restrict__ gcnt, unsigned* __restrict__ ggo,
    unsigned* __restrict__ root,
    const float* __restrict__ gamma, const float* __restrict__ beta,
    float* __restrict__ out)
{
    // wave-private: 4 waves x 3 rows x 64 cols x 32 ch bf16 = 48 KB
    __shared__ __align__(16) unsigned short ltile[4][3][2048];
    __shared__ float red_s[4][32];
    __shared__ float red_q[4][32];
    __shared__ float sc_a[32];
    __shared__ float sc_b[32];

    int bid  = blockIdx.x;
    int xcd  = bid & 7;
    int idx  = bid >> 3;                 // 0..95
    int bsel = idx / 48;                 // 0..1
    int r48  = idx % 48;
    int cfg  = r48 >> 4;                 // 0..2
    int rowg = r48 & 15;
    int b    = xcd + 8 * bsel;
    int d    = cfg + 1;
    int i0   = rowg * 4;
    int grp  = cfg * 32 + xcd * 4 + (rowg >> 2);  // 8 XCD-local members

    int t    = threadIdx.x;
    int wv   = t >> 6;
    int lane = t & 63;
    int l15  = lane & 15;
    int quad = lane >> 4;
    int row  = i0 + wv;

    // ---- per-wave private staging: 3 rows x 4 chunks = 12 GLDS
    const unsigned short* xTb = xT + (size_t)b * IMG * 32;
    unsigned short* wtile = &ltile[wv][0][0];
#pragma unroll
    for (int j = 0; j < 3; j++) {
        int gi = (row + (j - 1) * d) & 63;
        const unsigned short* src = xTb + (size_t)gi * 2048;
#pragma unroll
        for (int k = 0; k < 4; k++)
            GLDS(src + k * 512 + lane * 8, wtile + j * 2048 + k * 512 + lane * 8);
    }

    // af weight loads overlap the GLDS latency (independent global reads)
    const unsigned short* pwc = pw + (size_t)cfg * 9 * 32 * 32;
    short8 af[2][9];
#pragma unroll
    for (int h = 0; h < 2; h++)
#pragma unroll
        for (int tap = 0; tap < 9; tap++)
            af[h][tap] = *(const short8*)(pwc + ((tap * 32 + h * 16 + l15) * 32 + quad * 8));

    // preload gamma/beta (shortens post-barrier critical path)
    float gam = 0.f, bet = 0.f;
    if (t < 32) { gam = gamma[cfg * 32 + t]; bet = beta[cfg * 32 + t]; }

    // per-wave drain: this wave's GLDS + af loads complete; no block barrier
    asm volatile("s_waitcnt vmcnt(0)" ::: "memory");
    __builtin_amdgcn_sched_barrier(0);

    float ss[2][4], qq[2][4];
#pragma unroll
    for (int h = 0; h < 2; h++)
#pragma unroll
        for (int r = 0; r < 4; r++) { ss[h][r] = 0.f; qq[h][r] = 0.f; }

    // y kept in regs: ypk[h][r][g] = bf16(cg=2g) | bf16(cg=2g+1)<<16
    unsigned ypk[2][4][2];

#pragma unroll
    for (int cgi = 0; cgi < 4; cgi++) {
        floatx4 a0 = {0.f, 0.f, 0.f, 0.f};
        floatx4 a1 = {0.f, 0.f, 0.f, 0.f};
#pragma unroll
        for (int du = 0; du < 3; du++) {
            // private row du of this wave (== global row (row+(du-1)*d)&63)
            const unsigned short* rbase = wtile + du * 2048 + quad * 8;
#pragma unroll
            for (int dv = 0; dv < 3; dv++) {
                int col = (cgi * 16 + l15 + (dv - 1) * d) & 63;
                short8 bf = *(const short8*)(rbase + col * 32);
                a0 = __builtin_amdgcn_mfma_f32_16x16x32_bf16(af[0][du * 3 + dv], bf, a0, 0, 0, 0);
                a1 = __builtin_amdgcn_mfma_f32_16x16x32_bf16(af[1][du * 3 + dv], bf, a1, 0, 0, 0);
            }
        }
#pragma unroll
        for (int r = 0; r < 4; r++) {
            float v0 = a0[r], v1 = a1[r];
            unsigned short h0 = f2bf(v0), h1 = f2bf(v1);
            if (cgi & 1) {
                ypk[0][r][cgi >> 1] |= (unsigned)h0 << 16;
                ypk[1][r][cgi >> 1] |= (unsigned)h1 << 16;
            } else {
                ypk[0][r][cgi >> 1] = (unsigned)h0;
                ypk[1][r][cgi >> 1] = (unsigned)h1;
            }
            ss[0][r] += v0; qq[0][r] = fmaf(v0, v0, qq[0][r]);
            ss[1][r] += v1; qq[1][r] = fmaf(v1, v1, qq[1][r]);
        }
    }

    // reduce over the 16 column-lanes -> per-oc row sums
#pragma unroll
    for (int h = 0; h < 2; h++)
#pragma unroll
        for (int r = 0; r < 4; r++) {
            float s = ss[h][r], q = qq[h][r];
            for (int m = 1; m < 16; m <<= 1) {
                s += __shfl_xor(s, m, 64);
                q += __shfl_xor(q, m, 64);
            }
            if (l15 == 0) {
                red_s[wv][h * 16 + quad * 4 + r] = s;
                red_q[wv][h * 16 + quad * 4 + r] = q;
            }
        }
    __syncthreads();

    // per-(block,channel) atomicAdd; each channel accumulator on its OWN line
    if (t < 32) {
        float S = red_s[0][t] + red_s[1][t] + red_s[2][t] + red_s[3][t];
        atomicAdd(&gsum[(cfg * 32 + t) * PAD], S);
    } else if (t < 64) {
        int o = t - 32;
        float Q = red_q[0][o] + red_q[1][o] + red_q[2][o] + red_q[3][o];
        atomicAdd(&gsq[(cfg * 32 + o) * PAD], Q);
    }
    __syncthreads();   // all waves' atomics completed (vmcnt 0) before arrive

    // ---- hierarchical per-cfg grid barrier (RELAXED, XCD-local spin lines)
    if (t == 0) {
        unsigned r = __hip_atomic_fetch_add(&gcnt[grp * PAD], 1u,
                                            __ATOMIC_RELAXED, __HIP_MEMORY_SCOPE_AGENT);
        if (r == 7u) {   // group complete -> bump this cfg's root
            unsigned rr = __hip_atomic_fetch_add(&root[cfg * PAD], 1u,
                                                 __ATOMIC_RELAXED, __HIP_MEMORY_SCOPE_AGENT);
            if (rr == 31u) {   // cfg complete -> release its 32 groups
                for (int gg = cfg * 32; gg < cfg * 32 + 32; gg++)
                    __hip_atomic_store(&ggo[gg * PAD], 1u,
                                       __ATOMIC_RELAXED, __HIP_MEMORY_SCOPE_AGENT);
            }
        }
        while (__hip_atomic_load(&ggo[grp * PAD], __ATOMIC_RELAXED,
                                 __HIP_MEMORY_SCOPE_AGENT) == 0u)
            __builtin_amdgcn_s_sleep(2);
    }
    __syncthreads();

    // ---- per-channel scale/shift (atomic loads: coherent at LLC)
    if (t < 32) {
        int ch = cfg * 32 + t;
        float S = __hip_atomic_load(&gsum[ch * PAD], __ATOMIC_RELAXED, __HIP_MEMORY_SCOPE_AGENT);
        float Q = __hip_atomic_load(&gsq[ch * PAD],  __ATOMIC_RELAXED, __HIP_MEMORY_SCOPE_AGENT);
        const float inv_n = 1.0f / (float)NPIX;
        float mean = S * inv_n;
        float var  = Q * inv_n - mean * mean;
        float a    = gam * rsqrtf(var + 1e-5f);
        sc_a[t] = a;
        sc_b[t] = bet - mean * a;
    }
    __syncthreads();

    // ---- BN + tanh straight from registers -> fp32 out.
#pragma unroll
    for (int h = 0; h < 2; h++)
#pragma unroll
        for (int r = 0; r < 4; r++) {
            int m0  = quad * 4 + r;
            int chl = h * 16 + m0;
            float a  = sc_a[chl];
            float bb = sc_b[chl];
            float* obase = out + ((size_t)b * COUT + cfg * 32 + chl) * IMG
                               + (size_t)row * WH + l15;
#pragma unroll
            for (int g = 0; g < 2; g++) {
                unsigned pk = ypk[h][r][g];
                obase[(2 * g) * 16]     = fast_tanh(fmaf(bf2f((unsigned short)(pk & 0xffffu)), a, bb));
                obase[(2 * g + 1) * 16] = fast_tanh(fmaf(bf2f((unsigned short)(pk >> 16)), a, bb));
            }
        }
}

extern "C" void kernel_launch(void* const* d_in, const int* in_sizes, int n_in,
                              void* d_out, int out_size, void* d_ws, size_t ws_size,
                              hipStream_t stream) {
    const float* x     = (const float*)d_in[0];
    const float* w     = (const float*)d_in[1];
    // d_in[2] = mask: tap positions known analytically (3x3 dilated, centered at 32)
    const float* gamma = (const float*)d_in[3];
    const float* beta  = (const float*)d_in[4];
    float* out = (float*)d_out;

    // transient state in d_ws — no d_out aliasing anywhere
    unsigned short* xT = (unsigned short*)d_ws;             // 2097152 bf16 (4 MB)
    unsigned short* pw = xT + XTELEMS;                      // 27648 bf16
    float* gsum = (float*)(pw + PWELEMS + 32);              // 96 lines
    float* gsq  = gsum + NGRP * PAD;                        // 96 lines
    unsigned* gcnt = (unsigned*)(gsq + NGRP * PAD);         // 96 lines
    unsigned* ggo  = gcnt + NGRP * PAD;                     // 96 lines
    unsigned* root = ggo + NGRP * PAD;                      // 3 lines

    prep_kernel<<<621, 256, 0, stream>>>(x, w, xT, pw, (unsigned*)gsum);
    conv_bn_kernel<<<NBLK, 256, 0, stream>>>(xT, pw, gsum, gsq, gcnt, ggo, root,
                                             gamma, beta, out);
}